// Round 7
// baseline (331.517 us; speedup 1.0000x reference)
//
#include <hip/hip_runtime.h>
#include <stdint.h>

#define TPE 4096
#define DM 512
#define HID 1408
#define NE 8

#define N4X   4194304   // 32768*512/4
#define N4W12 2883584   // 8*2816*512/4
#define N4W3  1441792   // 8*512*1408/4

typedef unsigned short u16;
typedef __attribute__((ext_vector_type(8))) __bf16 bf16x8;
typedef __attribute__((ext_vector_type(4))) float f32x4;

__device__ __forceinline__ u16 f2bf(float f) {
  union { float f; uint32_t u; } v; v.f = f;
  uint32_t u = v.u;
  u += 0x7fffu + ((u >> 16) & 1u);   // round-to-nearest-even
  return (u16)(u >> 16);
}

__device__ __forceinline__ void cvt4(const float* __restrict__ src,
                                     u16* __restrict__ dst, int off) {
  float4 v = reinterpret_cast<const float4*>(src)[off];
  union { u16 s[4]; uint2 u2; } o;
  o.s[0] = f2bf(v.x); o.s[1] = f2bf(v.y); o.s[2] = f2bf(v.z); o.s[3] = f2bf(v.w);
  reinterpret_cast<uint2*>(dst)[off] = o.u2;
}

// ---------------- f32 -> bf16 convert: x, w12, w3 (grid-stride) ------------
__global__ void cvt_all(const float* __restrict__ x, const float* __restrict__ w12,
                        const float* __restrict__ w3,
                        u16* __restrict__ xb, u16* __restrict__ w12b,
                        u16* __restrict__ w3b) {
  const int stride = gridDim.x * blockDim.x;
  const int i0 = blockIdx.x * blockDim.x + threadIdx.x;
  for (int j = i0; j < N4X; j += stride)   cvt4(x, xb, j);
  for (int j = i0; j < N4W12; j += stride) cvt4(w12, w12b, j);
  for (int j = i0; j < N4W3; j += stride)  cvt4(w3, w3b, j);
}

// ------------- global->LDS async stage, ROWS x 64 bf16 tile (4 waves) ------
// Row = 128 B. XOR swizzle at 16B-chunk granularity: global chunk c of row r
// lands at LDS chunk c^(r&7) -> b128 reads are 2-way aliased (free, m136).
template <int ROWS>
__device__ __forceinline__ void stage_tile64(u16* lds, const u16* g, int lda,
                                             int wave, int lane) {
  const int srow = lane >> 3;                 // 0..7 within 8-row window
  const int gchunk = (lane & 7) ^ srow;       // schunk ^ (grow & 7)
#pragma unroll
  for (int r = 0; r < ROWS / 32; ++r) {
    const int row0 = (wave * (ROWS / 32) + r) * 8;
    const u16* gp = g + (size_t)(row0 + srow) * lda + gchunk * 8;
    u16* lp = lds + row0 * 64;                // 64 u16 (=128B) per row
    __builtin_amdgcn_global_load_lds((const __attribute__((address_space(1))) void*)gp,
                                     (__attribute__((address_space(3))) void*)lp,
                                     16, 0, 0);
  }
}

__device__ __forceinline__ bf16x8 read_frag(const u16* lds, int row, int kchunk) {
  return *reinterpret_cast<const bf16x8*>(&lds[row * 64 + (((kchunk ^ (row & 7)) << 3))]);
}

// ---------------- GEMM1 + fused SwiGLU, XCD-pinned per expert --------------
// (proven structure: 116 us / MfmaUtil 36% / 0 bank conflicts; tail removed)
// grid (8, 352): blockIdx.x = e -> with flat%8 XCD round-robin, expert e's
// blocks all land on XCD e, so w12_e (2.9 MB bf16) stays L2-resident.
// y = mt*11 + nt (nt fastest) -> each A-tile reused 11x while L2-hot.
__global__ __launch_bounds__(256, 2)
void gemm1_swiglu(const u16* __restrict__ xb, const u16* __restrict__ w12b,
                  u16* __restrict__ hb) {
  __shared__ u16 sA[128 * 64];
  __shared__ u16 sBg[128 * 64];
  __shared__ u16 sBu[128 * 64];
  const int e = blockIdx.x;
  const int y = blockIdx.y;
  const int tid = threadIdx.x;

  const int mt = y / 11, nt = y % 11;
  const int wave = tid >> 6, lane = tid & 63;
  const int wm = wave >> 1, wn = wave & 1;
  const int quad = lane >> 4, rr = lane & 15;

  const u16* A  = xb + (size_t)(e * TPE + mt * 128) * DM;
  const u16* Bg = w12b + (size_t)e * (2 * HID) * DM + (size_t)(nt * 128) * DM;
  const u16* Bu = Bg + (size_t)HID * DM;

  f32x4 zero = {0.f, 0.f, 0.f, 0.f};
  f32x4 accg[4][4], accu[4][4];
#pragma unroll
  for (int i = 0; i < 4; ++i)
#pragma unroll
    for (int j = 0; j < 4; ++j) { accg[i][j] = zero; accu[i][j] = zero; }

  for (int k0 = 0; k0 < DM; k0 += 64) {
    stage_tile64<128>(sA, A + k0, DM, wave, lane);
    stage_tile64<128>(sBg, Bg + k0, DM, wave, lane);
    stage_tile64<128>(sBu, Bu + k0, DM, wave, lane);
    __syncthreads();

#pragma unroll
    for (int kk = 0; kk < 2; ++kk) {
      const int kc = kk * 4 + quad;
      bf16x8 af[4], bg[4], bu[4];
#pragma unroll
      for (int mi = 0; mi < 4; ++mi)
        af[mi] = read_frag(sA, wm * 64 + mi * 16 + rr, kc);
#pragma unroll
      for (int ni = 0; ni < 4; ++ni) {
        bg[ni] = read_frag(sBg, wn * 64 + ni * 16 + rr, kc);
        bu[ni] = read_frag(sBu, wn * 64 + ni * 16 + rr, kc);
      }
#pragma unroll
      for (int mi = 0; mi < 4; ++mi)
#pragma unroll
        for (int ni = 0; ni < 4; ++ni) {
          accg[mi][ni] = __builtin_amdgcn_mfma_f32_16x16x32_bf16(af[mi], bg[ni], accg[mi][ni], 0, 0, 0);
          accu[mi][ni] = __builtin_amdgcn_mfma_f32_16x16x32_bf16(af[mi], bu[ni], accu[mi][ni], 0, 0, 0);
        }
    }
    __syncthreads();
  }

  const size_t rowbase = (size_t)(e * TPE + mt * 128 + wm * 64);
  const int colbase = nt * 128 + wn * 64;
#pragma unroll
  for (int mi = 0; mi < 4; ++mi)
#pragma unroll
    for (int ni = 0; ni < 4; ++ni)
#pragma unroll
      for (int r2 = 0; r2 < 4; ++r2) {
        float g = accg[mi][ni][r2];
        float u = accu[mi][ni][r2];
        float s = (g / (1.f + __expf(-g))) * u;
        size_t row = rowbase + mi * 16 + quad * 4 + r2;
        int col = colbase + ni * 16 + rr;
        hb[row * HID + col] = f2bf(s);
      }
}

// ---------------- GEMM2: h @ w3^T -> out (f32), 128x128, 4 blocks/CU -------
// Occupancy experiment: LDS 32 KB + 1024 blocks -> 4 resident blocks/CU
// (vs round-0's 2/CU at 48 KB). Per-CU MFMA work unchanged; per-step stage
// bytes drop 48->32 KB; m114 inter-block overlap depth doubles.
// grid (8, 128): x = e -> XCD pin (w3_e 1.4 MB L2-resident);
// y = mt*4 + nt (nt fastest -> hb A-tile reused 4x while L2-hot).
__global__ __launch_bounds__(256, 3)
void gemm2(const u16* __restrict__ hb, const u16* __restrict__ w3b,
           float* __restrict__ out) {
  __shared__ u16 sA[128 * 64];     // 16 KB
  __shared__ u16 sB[128 * 64];     // 16 KB
  const int e = blockIdx.x;
  const int mt = blockIdx.y >> 2, nt = blockIdx.y & 3;
  const int tid = threadIdx.x, wave = tid >> 6, lane = tid & 63;
  const int wm = wave >> 1, wn = wave & 1;
  const int quad = lane >> 4, rr = lane & 15;

  const u16* A = hb + (size_t)(e * TPE + mt * 128) * HID;
  const u16* B = w3b + (size_t)e * DM * HID + (size_t)(nt * 128) * HID;

  f32x4 zero = {0.f, 0.f, 0.f, 0.f};
  f32x4 acc[4][4];
#pragma unroll
  for (int i = 0; i < 4; ++i)
#pragma unroll
    for (int j = 0; j < 4; ++j) acc[i][j] = zero;

  for (int k0 = 0; k0 < HID; k0 += 64) {
    stage_tile64<128>(sA, A + k0, HID, wave, lane);
    stage_tile64<128>(sB, B + k0, HID, wave, lane);
    __syncthreads();

#pragma unroll
    for (int kk = 0; kk < 2; ++kk) {
      const int kc = kk * 4 + quad;
      bf16x8 af[4], bfr[4];
#pragma unroll
      for (int mi = 0; mi < 4; ++mi)
        af[mi] = read_frag(sA, wm * 64 + mi * 16 + rr, kc);
#pragma unroll
      for (int ni = 0; ni < 4; ++ni)
        bfr[ni] = read_frag(sB, wn * 64 + ni * 16 + rr, kc);
#pragma unroll
      for (int mi = 0; mi < 4; ++mi)
#pragma unroll
        for (int ni = 0; ni < 4; ++ni)
          acc[mi][ni] = __builtin_amdgcn_mfma_f32_16x16x32_bf16(af[mi], bfr[ni], acc[mi][ni], 0, 0, 0);
    }
    __syncthreads();
  }

  const size_t rowbase = (size_t)(e * TPE + mt * 128 + wm * 64);
  const int colbase = nt * 128 + wn * 64;
#pragma unroll
  for (int mi = 0; mi < 4; ++mi)
#pragma unroll
    for (int ni = 0; ni < 4; ++ni)
#pragma unroll
      for (int r2 = 0; r2 < 4; ++r2) {
        size_t row = rowbase + mi * 16 + quad * 4 + r2;
        int col = colbase + ni * 16 + rr;
        out[row * DM + col] = acc[mi][ni][r2];
      }
}

// ---------------------------------------------------------------------------
extern "C" void kernel_launch(void* const* d_in, const int* in_sizes, int n_in,
                              void* d_out, int out_size, void* d_ws, size_t ws_size,
                              hipStream_t stream) {
  (void)in_sizes; (void)n_in; (void)out_size; (void)ws_size;
  const float* x   = (const float*)d_in[0];
  const float* w12 = (const float*)d_in[1];
  const float* w3  = (const float*)d_in[2];
  float* out = (float*)d_out;

  char* ws = (char*)d_ws;
  u16* xb   = (u16*)(ws);
  u16* w12b = (u16*)(ws + (size_t)33554432);
  u16* w3b  = (u16*)(ws + (size_t)33554432 + 23068672);
  u16* hb   = (u16*)(ws + (size_t)33554432 + 23068672 + 11534336);

  cvt_all<<<2048, 256, 0, stream>>>(x, w12, w3, xb, w12b, w3b);
  // gemm1: XCD-pinned (x=e); y = mt*11+nt
  gemm1_swiglu<<<dim3(8, 352), 256, 0, stream>>>(xb, w12b, hb);
  // gemm2: XCD-pinned; 1024 blocks -> 4/CU
  gemm2<<<dim3(8, 128), 256, 0, stream>>>(hb, w3b, out);
}